// Round 2
// baseline (347.766 us; speedup 1.0000x reference)
//
#include <hip/hip_runtime.h>
#include <hip/hip_bf16.h>
#include <math.h>

// Problem constants
#define Hn 256
#define Nn 64
#define Bn 4
#define Ln 2048
#define Cn 64      // chunk length
#define NC 32      // chunks per sequence (Ln/Cn)

// ---------------------------------------------------------------------------
// K0a: per (h,n) parameters: a = exp(s), G[h][j][n] = CB * a^(j+1),
//      Krow[h][t] = Re(sum_n CB * a^t)  (t = 0..63)
// grid: H blocks x 64 threads (lane = n)
// ---------------------------------------------------------------------------
__global__ void k_precompute(const float* __restrict__ lnr, const float* __restrict__ im,
                             const float* __restrict__ Bre, const float* __restrict__ Bim,
                             const float* __restrict__ Cre, const float* __restrict__ Cim,
                             const float* __restrict__ lstep,
                             float* __restrict__ G, float* __restrict__ apar,
                             float* __restrict__ Krow)
{
    int h = blockIdx.x;
    int n = threadIdx.x;
    __shared__ float kacc[64][65];

    float st  = fminf(fmaxf(expf(lstep[h]), 1e-5f), 1.0f);
    float lam = -expf(lnr[n]);
    float sre = st * lam;
    float sim = st * im[n];
    float er  = expf(sre);
    float ar  = er * cosf(sim);
    float ai  = er * sinf(sim);
    float bre = Bre[h * Nn + n] * st;
    float bim = Bim[h * Nn + n] * st;
    float cr  = Cre[h * Nn + n];
    float ci  = Cim[h * Nn + n];
    float CBr = cr * bre - ci * bim;
    float CBi = cr * bim + ci * bre;

    apar[(h * Nn + n) * 2]     = ar;
    apar[(h * Nn + n) * 2 + 1] = ai;

    float Pr = ar, Pi = ai;   // a^(j+1), starting a^1
    float Qr = 1.f, Qi = 0.f; // a^t, starting a^0
    for (int j = 0; j < 64; ++j) {
        float gr = CBr * Pr - CBi * Pi;
        float gi = CBr * Pi + CBi * Pr;
        G[((h * 64 + j) * 64 + n) * 2]     = gr;
        G[((h * 64 + j) * 64 + n) * 2 + 1] = gi;
        kacc[j][n] = CBr * Qr - CBi * Qi;
        float npr = Pr * ar - Pi * ai; Pi = Pr * ai + Pi * ar; Pr = npr;
        float nqr = Qr * ar - Qi * ai; Qi = Qr * ai + Qi * ar; Qr = nqr;
    }
    __syncthreads();
    // lane t sums kacc[t][*] over n
    float s = 0.f;
    #pragma unroll
    for (int m = 0; m < 64; ++m) s += kacc[n][m];
    Krow[h * 64 + n] = s;
}

// ---------------------------------------------------------------------------
// K0b: transpose u (B,L,H) -> uT (B,H,L), 64x64 LDS tiles
// ---------------------------------------------------------------------------
__global__ void k_transpose(const float* __restrict__ u, float* __restrict__ uT)
{
    __shared__ float tile[64][65];
    int b  = blockIdx.z;
    int l0 = blockIdx.x * 64;
    int h0 = blockIdx.y * 64;
    int t  = threadIdx.x;
    int col = t & 63, rbase = t >> 6;
    for (int r = rbase; r < 64; r += 4)
        tile[r][col] = u[(b * Ln + l0 + r) * Hn + h0 + col];
    __syncthreads();
    for (int r = rbase; r < 64; r += 4)
        uT[(b * Hn + h0 + r) * Ln + l0 + col] = tile[col][r];
}

// ---------------------------------------------------------------------------
// K1: sequential scan per (b,h): x_l = a x_{l-1} + u_l, storing chunk-boundary
//     states S[bh][c][n] = x_{64c-1} (S[.][0] = 0). lane = n.
// ---------------------------------------------------------------------------
__global__ void k_scan(const float* __restrict__ uT, const float* __restrict__ apar,
                       float* __restrict__ S)
{
    int bh = blockIdx.x;
    int h  = bh & (Hn - 1);
    int n  = threadIdx.x;
    float ar = apar[(h * Nn + n) * 2];
    float ai = apar[(h * Nn + n) * 2 + 1];
    float a2r = ar * ar - ai * ai;
    float a2i = 2.f * ar * ai;
    const float* uR = uT + bh * Ln;
    float xr = 0.f, xi = 0.f;
    for (int c = 0; c < NC; ++c) {
        float2* Sp = (float2*)S + (bh * NC + c) * Nn;
        Sp[n] = make_float2(xr, xi);
        const float* up = uR + c * Cn;
        #pragma unroll
        for (int t = 0; t < Cn; t += 2) {
            float u1 = up[t];
            float u2 = up[t + 1];
            float crr = fmaf(ar, u1, u2);
            float cii = ai * u1;
            float nxr = fmaf(a2r, xr, fmaf(-a2i, xi, crr));
            float nxi = fmaf(a2i, xr, fmaf(a2r, xi, cii));
            xr = nxr; xi = nxi;
        }
    }
}

// ---------------------------------------------------------------------------
// K2: per-chunk outputs. block = (b,h), 4 waves, wave w does chunks {w, w+4,...}
// ---------------------------------------------------------------------------
__global__ __launch_bounds__(256, 2)
void k_chunks(const float* __restrict__ uT, const float* __restrict__ S,
              const float* __restrict__ G, const float* __restrict__ Krow,
              const float* __restrict__ D, float* __restrict__ ypre)
{
    int bh = blockIdx.x;
    int h  = bh & (Hn - 1);
    int j  = threadIdx.x & 63;
    int w  = __builtin_amdgcn_readfirstlane(threadIdx.x >> 6);

    __shared__ float kbuf[128];
    if (threadIdx.x < 64) kbuf[threadIdx.x] = 0.f;
    else if (threadIdx.x < 128) kbuf[threadIdx.x] = Krow[h * 64 + threadIdx.x - 64];
    __syncthreads();

    float2 Greg[64];
    const float2* Gp = (const float2*)G + (h * 64 + j) * 64;
    #pragma unroll
    for (int n = 0; n < 64; ++n) Greg[n] = Gp[n];

    float Dh = D[h];

    for (int k = 0; k < 8; ++k) {
        int c = (k << 2) | w;                       // wave-uniform chunk id
        const float2* Sp = (const float2*)S + (bh * NC + c) * Nn;
        const float* up  = uT + bh * Ln + c * Cn;
        float uv = up[j];
        float y = 0.f;
        #pragma unroll
        for (int n = 0; n < 64; ++n) {
            float2 sv = Sp[n];                      // wave-uniform -> scalar load
            y = fmaf(Greg[n].x, sv.x, y);
            y = fmaf(-Greg[n].y, sv.y, y);
        }
        #pragma unroll
        for (int m = 0; m < 64; ++m) {
            y = fmaf(kbuf[64 + j - m], up[m], y);   // up[m] wave-uniform
        }
        float yv = fmaf(Dh, uv, y);
        float g  = 0.5f * yv * (1.f + erff(yv * 0.70710678118654752f));
        ypre[bh * Ln + c * Cn + j] = g;
    }
}

// ---------------------------------------------------------------------------
// K3: LayerNorm over H with transpose read; fp32 output (B,L,H).
// ---------------------------------------------------------------------------
__global__ void k_ln(const float* __restrict__ ypre, const float* __restrict__ gamma,
                     const float* __restrict__ beta, float* __restrict__ out)
{
    __shared__ float tile[Hn * 33];
    int b  = blockIdx.y;
    int l0 = blockIdx.x * 32;
    int t  = threadIdx.x;
    for (int i = 0; i < 32; ++i) {
        int idx = i * 256 + t;
        int hh = idx >> 5, lo = idx & 31;
        tile[hh * 33 + lo] = ypre[(b * Hn + hh) * Ln + l0 + lo];
    }
    __syncthreads();
    int wv = t >> 6, lane = t & 63;
    for (int k = 0; k < 8; ++k) {
        int l = (k << 2) | wv;
        float v[4];
        float sum = 0.f, sq = 0.f;
        #pragma unroll
        for (int i = 0; i < 4; ++i) {
            int hh = lane + (i << 6);
            v[i] = tile[hh * 33 + l];
            sum += v[i];
            sq = fmaf(v[i], v[i], sq);
        }
        #pragma unroll
        for (int off = 32; off; off >>= 1) {
            sum += __shfl_xor(sum, off);
            sq  += __shfl_xor(sq, off);
        }
        float mean = sum * (1.f / 256.f);
        float var  = sq * (1.f / 256.f) - mean * mean;
        float rs   = rsqrtf(var + 1e-5f);
        #pragma unroll
        for (int i = 0; i < 4; ++i) {
            int hh = lane + (i << 6);
            float o = (v[i] - mean) * rs * gamma[hh] + beta[hh];
            out[(b * Ln + l0 + l) * Hn + hh] = o;
        }
    }
}

// ---------------------------------------------------------------------------
extern "C" void kernel_launch(void* const* d_in, const int* in_sizes, int n_in,
                              void* d_out, int out_size, void* d_ws, size_t ws_size,
                              hipStream_t stream)
{
    const float* u     = (const float*)d_in[0];
    const float* lnr   = (const float*)d_in[1];
    const float* im    = (const float*)d_in[2];
    const float* Bre   = (const float*)d_in[3];
    const float* Bim   = (const float*)d_in[4];
    const float* Cre   = (const float*)d_in[5];
    const float* Cim   = (const float*)d_in[6];
    const float* Dp    = (const float*)d_in[7];
    const float* lstep = (const float*)d_in[8];
    const float* gam   = (const float*)d_in[9];
    const float* bet   = (const float*)d_in[10];
    float* out = (float*)d_out;

    // workspace carve (floats)
    float* ws   = (float*)d_ws;
    float* uT   = ws;                                  // B*H*L        = 2097152
    float* S    = uT   + (size_t)Bn * Hn * Ln;         // B*H*NC*N*2   = 4194304
    float* G    = S    + (size_t)Bn * Hn * NC * Nn * 2;// H*64*N*2     = 2097152
    float* apar = G    + (size_t)Hn * 64 * Nn * 2;     // H*N*2        = 32768
    float* Krow = apar + (size_t)Hn * Nn * 2;          // H*64         = 16384
    float* ypre = Krow + (size_t)Hn * 64;              // B*H*L        = 2097152

    k_precompute<<<Hn, 64, 0, stream>>>(lnr, im, Bre, Bim, Cre, Cim, lstep, G, apar, Krow);
    k_transpose<<<dim3(Ln / 64, Hn / 64, Bn), 256, 0, stream>>>(u, uT);
    k_scan<<<Bn * Hn, 64, 0, stream>>>(uT, apar, S);
    k_chunks<<<Bn * Hn, 256, 0, stream>>>(uT, S, G, Krow, Dp, ypre);
    k_ln<<<dim3(Ln / 32, Bn), 256, 0, stream>>>(ypre, gam, bet, out);
}

// Round 3
// 153.517 us; speedup vs baseline: 2.2653x; 2.2653x over previous
//
#include <hip/hip_runtime.h>
#include <hip/hip_bf16.h>
#include <math.h>

// Problem constants
#define Hn 256
#define Nn 64
#define Bn 4
#define Ln 2048
#define Cn 64      // chunk length
#define NC 32      // chunks per sequence (Ln/Cn)

// ---------------------------------------------------------------------------
// K0a: per (h,n) parameters: a = exp(s), G[h][j][n] = CB * a^(j+1),
//      Krow[h][t] = Re(sum_n CB * a^t)  (t = 0..63)
// grid: H blocks x 64 threads (lane = n)
// ---------------------------------------------------------------------------
__global__ void k_precompute(const float* __restrict__ lnr, const float* __restrict__ im,
                             const float* __restrict__ Bre, const float* __restrict__ Bim,
                             const float* __restrict__ Cre, const float* __restrict__ Cim,
                             const float* __restrict__ lstep,
                             float* __restrict__ G, float* __restrict__ apar,
                             float* __restrict__ Krow)
{
    int h = blockIdx.x;
    int n = threadIdx.x;
    __shared__ float kacc[64][65];

    float st  = fminf(fmaxf(expf(lstep[h]), 1e-5f), 1.0f);
    float lam = -expf(lnr[n]);
    float sre = st * lam;
    float sim = st * im[n];
    float er  = expf(sre);
    float ar  = er * cosf(sim);
    float ai  = er * sinf(sim);
    float bre = Bre[h * Nn + n] * st;
    float bim = Bim[h * Nn + n] * st;
    float cr  = Cre[h * Nn + n];
    float ci  = Cim[h * Nn + n];
    float CBr = cr * bre - ci * bim;
    float CBi = cr * bim + ci * bre;

    apar[(h * Nn + n) * 2]     = ar;
    apar[(h * Nn + n) * 2 + 1] = ai;

    float Pr = ar, Pi = ai;   // a^(j+1), starting a^1
    float Qr = 1.f, Qi = 0.f; // a^t, starting a^0
    for (int j = 0; j < 64; ++j) {
        float gr = CBr * Pr - CBi * Pi;
        float gi = CBr * Pi + CBi * Pr;
        G[((h * 64 + j) * 64 + n) * 2]     = gr;
        G[((h * 64 + j) * 64 + n) * 2 + 1] = gi;
        kacc[j][n] = CBr * Qr - CBi * Qi;
        float npr = Pr * ar - Pi * ai; Pi = Pr * ai + Pi * ar; Pr = npr;
        float nqr = Qr * ar - Qi * ai; Qi = Qr * ai + Qi * ar; Qr = nqr;
    }
    __syncthreads();
    // lane t sums kacc[t][*] over n
    float s = 0.f;
    #pragma unroll
    for (int m = 0; m < 64; ++m) s += kacc[n][m];
    Krow[h * 64 + n] = s;
}

// ---------------------------------------------------------------------------
// K0b: transpose u (B,L,H) -> uT (B,H,L), 64x64 LDS tiles
// ---------------------------------------------------------------------------
__global__ void k_transpose(const float* __restrict__ u, float* __restrict__ uT)
{
    __shared__ float tile[64][65];
    int b  = blockIdx.z;
    int l0 = blockIdx.x * 64;
    int h0 = blockIdx.y * 64;
    int t  = threadIdx.x;
    int col = t & 63, rbase = t >> 6;
    for (int r = rbase; r < 64; r += 4)
        tile[r][col] = u[(b * Ln + l0 + r) * Hn + h0 + col];
    __syncthreads();
    for (int r = rbase; r < 64; r += 4)
        uT[(b * Hn + h0 + r) * Ln + l0 + col] = tile[col][r];
}

// ---------------------------------------------------------------------------
// K1: sequential scan per (b,h): x_l = a x_{l-1} + u_l, storing chunk-boundary
//     states S[bh][c][n] = x_{64c-1} (S[.][0] = 0). lane = n.
// ---------------------------------------------------------------------------
__global__ void k_scan(const float* __restrict__ uT, const float* __restrict__ apar,
                       float* __restrict__ S)
{
    int bh = blockIdx.x;
    int h  = bh & (Hn - 1);
    int n  = threadIdx.x;
    float ar = apar[(h * Nn + n) * 2];
    float ai = apar[(h * Nn + n) * 2 + 1];
    float a2r = ar * ar - ai * ai;
    float a2i = 2.f * ar * ai;
    const float* uR = uT + bh * Ln;
    float xr = 0.f, xi = 0.f;
    for (int c = 0; c < NC; ++c) {
        float2* Sp = (float2*)S + (bh * NC + c) * Nn;
        Sp[n] = make_float2(xr, xi);
        const float* up = uR + c * Cn;
        #pragma unroll
        for (int t = 0; t < Cn; t += 2) {
            float u1 = up[t];
            float u2 = up[t + 1];
            float crr = fmaf(ar, u1, u2);
            float cii = ai * u1;
            float nxr = fmaf(a2r, xr, fmaf(-a2i, xi, crr));
            float nxi = fmaf(a2i, xr, fmaf(a2r, xi, cii));
            xr = nxr; xi = nxi;
        }
    }
}

// ---------------------------------------------------------------------------
// K2 (v2): per-chunk outputs, n-split across waves to kill register spill.
//   block = (b,h), 4 waves, lane = j. Wave w owns n,m in [16w, 16w+16):
//     - G slice (16 float2 = 32 VGPR) and 16 Toeplitz weights in registers
//     - S and conv-u values are wave-uniform -> scalar (SMEM) loads
//     - partial sums for all 32 chunks -> LDS -> cross-wave reduce + GELU
// ---------------------------------------------------------------------------
__global__ __launch_bounds__(256)
void k_chunks(const float* __restrict__ uT, const float* __restrict__ S,
              const float* __restrict__ G, const float* __restrict__ Krow,
              const float* __restrict__ D, float* __restrict__ ypre)
{
    int bh  = blockIdx.x;
    int h   = bh & (Hn - 1);
    int tid = threadIdx.x;
    int j   = tid & 63;
    int w   = __builtin_amdgcn_readfirstlane(tid >> 6);
    int n0  = w << 4;                               // wave's n/m slice start

    __shared__ float kbuf[128];                     // zero-padded Krow
    __shared__ float part[NC][4][64];               // 32 KB partials

    if (tid < 64) kbuf[tid] = 0.f;
    else if (tid < 128) kbuf[tid] = Krow[h * 64 + tid - 64];
    __syncthreads();

    // G slice: lane j reads 16 consecutive float2 (128 B) -> 32 VGPRs
    float2 Gr[16];
    const float2* Gp = (const float2*)G + ((h * 64 + j) * 64 + n0);
    #pragma unroll
    for (int i = 0; i < 16; ++i) Gr[i] = Gp[i];

    // Toeplitz weights: Kreg[i] = Krow[j - (n0+i)] (0 if negative)
    float Kreg[16];
    #pragma unroll
    for (int i = 0; i < 16; ++i) Kreg[i] = kbuf[64 + j - n0 - i];

    const float2* Sp_base = (const float2*)S + (size_t)(bh * NC) * Nn + n0;
    const float*  uRow    = uT + (size_t)bh * Ln;

    for (int c = 0; c < NC; ++c) {
        const float2* Sp = Sp_base + (size_t)c * Nn;    // wave-uniform
        const float*  uc = uRow + c * Cn + n0;          // wave-uniform
        float y0 = 0.f, y1 = 0.f, y2 = 0.f;
        #pragma unroll
        for (int i = 0; i < 16; ++i) {
            float2 sv = Sp[i];                          // scalar loads
            y0 = fmaf(Gr[i].x, sv.x, y0);
            y1 = fmaf(-Gr[i].y, sv.y, y1);
        }
        #pragma unroll
        for (int i = 0; i < 16; ++i) {
            y2 = fmaf(Kreg[i], uc[i], y2);              // uc[i] scalar load
        }
        part[c][w][j] = (y0 + y1) + y2;
    }
    __syncthreads();

    float Dh = D[h];
    for (int k = 0; k < 8; ++k) {
        int c = (k << 2) | w;
        float y = (part[c][0][j] + part[c][1][j]) + (part[c][2][j] + part[c][3][j]);
        float uv = uRow[c * Cn + j];
        float yv = fmaf(Dh, uv, y);
        float g  = 0.5f * yv * (1.f + erff(yv * 0.70710678118654752f));
        ypre[(size_t)bh * Ln + c * Cn + j] = g;
    }
}

// ---------------------------------------------------------------------------
// K3: LayerNorm over H with transpose read; fp32 output (B,L,H).
// ---------------------------------------------------------------------------
__global__ void k_ln(const float* __restrict__ ypre, const float* __restrict__ gamma,
                     const float* __restrict__ beta, float* __restrict__ out)
{
    __shared__ float tile[Hn * 33];
    int b  = blockIdx.y;
    int l0 = blockIdx.x * 32;
    int t  = threadIdx.x;
    for (int i = 0; i < 32; ++i) {
        int idx = i * 256 + t;
        int hh = idx >> 5, lo = idx & 31;
        tile[hh * 33 + lo] = ypre[(b * Hn + hh) * Ln + l0 + lo];
    }
    __syncthreads();
    int wv = t >> 6, lane = t & 63;
    for (int k = 0; k < 8; ++k) {
        int l = (k << 2) | wv;
        float v[4];
        float sum = 0.f, sq = 0.f;
        #pragma unroll
        for (int i = 0; i < 4; ++i) {
            int hh = lane + (i << 6);
            v[i] = tile[hh * 33 + l];
            sum += v[i];
            sq = fmaf(v[i], v[i], sq);
        }
        #pragma unroll
        for (int off = 32; off; off >>= 1) {
            sum += __shfl_xor(sum, off);
            sq  += __shfl_xor(sq, off);
        }
        float mean = sum * (1.f / 256.f);
        float var  = sq * (1.f / 256.f) - mean * mean;
        float rs   = rsqrtf(var + 1e-5f);
        #pragma unroll
        for (int i = 0; i < 4; ++i) {
            int hh = lane + (i << 6);
            float o = (v[i] - mean) * rs * gamma[hh] + beta[hh];
            out[(b * Ln + l0 + l) * Hn + hh] = o;
        }
    }
}

// ---------------------------------------------------------------------------
extern "C" void kernel_launch(void* const* d_in, const int* in_sizes, int n_in,
                              void* d_out, int out_size, void* d_ws, size_t ws_size,
                              hipStream_t stream)
{
    const float* u     = (const float*)d_in[0];
    const float* lnr   = (const float*)d_in[1];
    const float* im    = (const float*)d_in[2];
    const float* Bre   = (const float*)d_in[3];
    const float* Bim   = (const float*)d_in[4];
    const float* Cre   = (const float*)d_in[5];
    const float* Cim   = (const float*)d_in[6];
    const float* Dp    = (const float*)d_in[7];
    const float* lstep = (const float*)d_in[8];
    const float* gam   = (const float*)d_in[9];
    const float* bet   = (const float*)d_in[10];
    float* out = (float*)d_out;

    // workspace carve (floats)
    float* ws   = (float*)d_ws;
    float* uT   = ws;                                  // B*H*L        = 2097152
    float* S    = uT   + (size_t)Bn * Hn * Ln;         // B*H*NC*N*2   = 4194304
    float* G    = S    + (size_t)Bn * Hn * NC * Nn * 2;// H*64*N*2     = 2097152
    float* apar = G    + (size_t)Hn * 64 * Nn * 2;     // H*N*2        = 32768
    float* Krow = apar + (size_t)Hn * Nn * 2;          // H*64         = 16384
    float* ypre = Krow + (size_t)Hn * 64;              // B*H*L        = 2097152

    k_precompute<<<Hn, 64, 0, stream>>>(lnr, im, Bre, Bim, Cre, Cim, lstep, G, apar, Krow);
    k_transpose<<<dim3(Ln / 64, Hn / 64, Bn), 256, 0, stream>>>(u, uT);
    k_scan<<<Bn * Hn, 64, 0, stream>>>(uT, apar, S);
    k_chunks<<<Bn * Hn, 256, 0, stream>>>(uT, S, G, Krow, Dp, ypre);
    k_ln<<<dim3(Ln / 32, Bn), 256, 0, stream>>>(ypre, gam, bet, out);
}

// Round 4
// 136.773 us; speedup vs baseline: 2.5427x; 1.1224x over previous
//
#include <hip/hip_runtime.h>
#include <hip/hip_bf16.h>
#include <math.h>

// Problem constants
#define Hn 256
#define Nn 64
#define Bn 4
#define Ln 2048
#define Cn 64      // chunk length
#define NC 32      // chunks per sequence (Ln/Cn)

// ---------------------------------------------------------------------------
// K0 (merged): blocks [0,512): transpose u (B,L,H)->uT (B,H,L) in 64x64 tiles.
//              blocks [512,768): per-h parameter precompute:
//                a = exp(step*Lam), G[h][j][n] = CB*a^(j+1) (complex),
//                Krow[h][t] = Re(sum_n CB*a^t), apar[h][n] = a.
// ---------------------------------------------------------------------------
__global__ __launch_bounds__(256)
void k_pre(const float* __restrict__ u, float* __restrict__ uT,
           const float* __restrict__ lnr, const float* __restrict__ im,
           const float* __restrict__ Bre, const float* __restrict__ Bim,
           const float* __restrict__ Cre, const float* __restrict__ Cim,
           const float* __restrict__ lstep,
           float* __restrict__ G, float* __restrict__ apar,
           float* __restrict__ Krow)
{
    __shared__ float sh[64 * 65];
    int bid = blockIdx.x;
    int t   = threadIdx.x;

    if (bid < 512) {
        // ---- transpose tile ----
        int b  = bid >> 7;
        int h0 = ((bid >> 5) & 3) * 64;
        int l0 = (bid & 31) * 64;
        int col = t & 63, rbase = t >> 6;
        for (int r = rbase; r < 64; r += 4)
            sh[r * 65 + col] = u[((size_t)b * Ln + l0 + r) * Hn + h0 + col];
        __syncthreads();
        for (int r = rbase; r < 64; r += 4)
            uT[((size_t)b * Hn + h0 + r) * Ln + l0 + col] = sh[col * 65 + r];
    } else {
        // ---- precompute for h = bid-512 (one wave active) ----
        int h = bid - 512;
        int n = t;
        if (t < 64) {
            float st  = fminf(fmaxf(expf(lstep[h]), 1e-5f), 1.0f);
            float lam = -expf(lnr[n]);
            float er  = expf(st * lam);
            float sim = st * im[n];
            float ar  = er * cosf(sim);
            float ai  = er * sinf(sim);
            float bre = Bre[h * Nn + n] * st;
            float bim = Bim[h * Nn + n] * st;
            float cr  = Cre[h * Nn + n];
            float ci  = Cim[h * Nn + n];
            float CBr = cr * bre - ci * bim;
            float CBi = cr * bim + ci * bre;

            apar[(h * Nn + n) * 2]     = ar;
            apar[(h * Nn + n) * 2 + 1] = ai;

            float Pr = ar, Pi = ai;   // a^(j+1)
            float Qr = 1.f, Qi = 0.f; // a^j
            for (int j = 0; j < 64; ++j) {
                G[((h * 64 + j) * 64 + n) * 2]     = CBr * Pr - CBi * Pi;
                G[((h * 64 + j) * 64 + n) * 2 + 1] = CBr * Pi + CBi * Pr;
                sh[j * 65 + n] = CBr * Qr - CBi * Qi;   // kacc[j][n]
                float npr = Pr * ar - Pi * ai; Pi = Pr * ai + Pi * ar; Pr = npr;
                float nqr = Qr * ar - Qi * ai; Qi = Qr * ai + Qi * ar; Qr = nqr;
            }
        }
        __syncthreads();
        if (t < 64) {
            float s = 0.f;
            #pragma unroll
            for (int m = 0; m < 64; ++m) s += sh[t * 65 + m];
            Krow[h * 64 + t] = s;
        }
    }
}

// ---------------------------------------------------------------------------
// K1 (fused scan+chunks). block = (b,h), 4 waves x 64 lanes.
//  Phase 1 (lane = n): wave w scans segment [512w, 512w+512) with zero start,
//    keeping local chunk-boundary states Sloc[0..8) in regs and writing the
//    segment-final state F_w to LDS.
//  Combine: X_0=0, X_{s+1} = a^512 X_s + F_s (per lane n);
//    true S[8w+k] = Sloc[k] + a^{64k} X_w  -> S_lds[32][64] (exact linearity).
//  Phase 2 (lane = j): wave w owns n,m-slice [16w,16w+16):
//    y_part = sum_i Re(G[j,n0+i] * S[c][n0+i]) + sum_i Krow[j-n0-i]*u[c*64+n0+i]
//    partials -> LDS -> cross-wave reduce, +D*u, exact GELU, store ypre[b,h,l].
// ---------------------------------------------------------------------------
__global__ __launch_bounds__(256)
void k_scan_chunks(const float* __restrict__ uT, const float* __restrict__ apar,
                   const float* __restrict__ G, const float* __restrict__ Krow,
                   const float* __restrict__ D, float* __restrict__ ypre)
{
    int bh  = blockIdx.x;
    int h   = bh & (Hn - 1);
    int tid = threadIdx.x;
    int j   = tid & 63;                              // lane id (n in phase 1)
    int w   = __builtin_amdgcn_readfirstlane(tid >> 6);
    int n0  = w << 4;

    __shared__ float  kbuf[128];          // zero-padded Krow
    __shared__ float2 S_lds[NC][64];      // 16 KB true chunk states
    __shared__ float2 F_lds[4][64];       // 2 KB segment finals
    __shared__ float  part[NC][4][64];    // 32 KB phase-2 partials

    if (tid < 64) kbuf[tid] = 0.f;
    else if (tid < 128) kbuf[tid] = Krow[h * 64 + tid - 64];

    // ---- phase 1: segmented scan (lane = n) ----
    int n = j;
    float ar = apar[(h * Nn + n) * 2];
    float ai = apar[(h * Nn + n) * 2 + 1];
    float a2r = ar * ar - ai * ai;
    float a2i = 2.f * ar * ai;
    const float* uRow = uT + (size_t)bh * Ln;
    const float* useg = uRow + (w << 9);

    float2 Sloc[8];
    float xr = 0.f, xi = 0.f;
    #pragma unroll
    for (int k = 0; k < 8; ++k) {
        Sloc[k] = make_float2(xr, xi);
        const float* up = useg + (k << 6);
        #pragma unroll
        for (int tt = 0; tt < 64; tt += 2) {
            float u1 = up[tt], u2 = up[tt + 1];
            float crr = fmaf(ar, u1, u2);
            float cii = ai * u1;
            float nxr = fmaf(a2r, xr, fmaf(-a2i, xi, crr));
            float nxi = fmaf(a2i, xr, fmaf(a2r, xi, cii));
            xr = nxr; xi = nxi;
        }
    }
    F_lds[w][n] = make_float2(xr, xi);
    __syncthreads();

    // a^64 (6 squarings), p = a^512 (3 more)
    float b_r = ar, b_i = ai;
    #pragma unroll
    for (int q = 0; q < 6; ++q) { float nr = b_r * b_r - b_i * b_i; b_i = 2.f * b_r * b_i; b_r = nr; }
    float p_r = b_r, p_i = b_i;
    #pragma unroll
    for (int q = 0; q < 3; ++q) { float nr = p_r * p_r - p_i * p_i; p_i = 2.f * p_r * p_i; p_r = nr; }

    // X_w = fold_{t<w} X = p*X + F_t   (wave-uniform trip count)
    float Xr = 0.f, Xi = 0.f;
    for (int s = 0; s < w; ++s) {
        float2 Ft = F_lds[s][n];
        float nXr = fmaf(p_r, Xr, fmaf(-p_i, Xi, Ft.x));
        float nXi = fmaf(p_i, Xr, fmaf(p_r, Xi, Ft.y));
        Xr = nXr; Xi = nXi;
    }

    // true states: S[8w+k] = Sloc[k] + a^{64k} * X
    float e_r = 1.f, e_i = 0.f;
    #pragma unroll
    for (int k = 0; k < 8; ++k) {
        float sr = Sloc[k].x + (e_r * Xr - e_i * Xi);
        float si = Sloc[k].y + (e_r * Xi + e_i * Xr);
        S_lds[(w << 3) + k][n] = make_float2(sr, si);
        float nr = e_r * b_r - e_i * b_i;
        e_i = e_r * b_i + e_i * b_r;
        e_r = nr;
    }
    __syncthreads();

    // ---- phase 2 (lane = j) ----
    float2 Gr[16];
    const float2* Gp = (const float2*)G + ((h * 64 + j) * 64 + n0);
    #pragma unroll
    for (int i = 0; i < 16; ++i) Gr[i] = Gp[i];
    float Kreg[16];
    #pragma unroll
    for (int i = 0; i < 16; ++i) Kreg[i] = kbuf[64 + j - n0 - i];

    for (int c = 0; c < NC; ++c) {
        const float2* Sp = &S_lds[c][n0];        // wave-uniform LDS broadcast
        const float*  uc = uRow + (c << 6) + n0; // wave-uniform -> scalar loads
        float y0 = 0.f, y1 = 0.f, y2 = 0.f;
        #pragma unroll
        for (int i = 0; i < 16; ++i) {
            float2 sv = Sp[i];
            y0 = fmaf(Gr[i].x, sv.x, y0);
            y1 = fmaf(-Gr[i].y, sv.y, y1);
        }
        #pragma unroll
        for (int i = 0; i < 16; ++i) y2 = fmaf(Kreg[i], uc[i], y2);
        part[c][w][j] = (y0 + y1) + y2;
    }
    __syncthreads();

    float Dh = D[h];
    for (int k = 0; k < 8; ++k) {
        int c = (k << 2) | w;
        float y  = (part[c][0][j] + part[c][1][j]) + (part[c][2][j] + part[c][3][j]);
        float uv = uRow[(c << 6) + j];
        float yv = fmaf(Dh, uv, y);
        float g  = 0.5f * yv * (1.f + erff(yv * 0.70710678118654752f));
        ypre[(size_t)bh * Ln + (c << 6) + j] = g;
    }
}

// ---------------------------------------------------------------------------
// K2: LayerNorm over H with transpose read; fp32 output (B,L,H).
// ---------------------------------------------------------------------------
__global__ void k_ln(const float* __restrict__ ypre, const float* __restrict__ gamma,
                     const float* __restrict__ beta, float* __restrict__ out)
{
    __shared__ float tile[Hn * 33];
    int b  = blockIdx.y;
    int l0 = blockIdx.x * 32;
    int t  = threadIdx.x;
    for (int i = 0; i < 32; ++i) {
        int idx = i * 256 + t;
        int hh = idx >> 5, lo = idx & 31;
        tile[hh * 33 + lo] = ypre[((size_t)b * Hn + hh) * Ln + l0 + lo];
    }
    __syncthreads();
    int wv = t >> 6, lane = t & 63;
    for (int k = 0; k < 8; ++k) {
        int l = (k << 2) | wv;
        float v[4];
        float sum = 0.f, sq = 0.f;
        #pragma unroll
        for (int i = 0; i < 4; ++i) {
            int hh = lane + (i << 6);
            v[i] = tile[hh * 33 + l];
            sum += v[i];
            sq = fmaf(v[i], v[i], sq);
        }
        #pragma unroll
        for (int off = 32; off; off >>= 1) {
            sum += __shfl_xor(sum, off);
            sq  += __shfl_xor(sq, off);
        }
        float mean = sum * (1.f / 256.f);
        float var  = sq * (1.f / 256.f) - mean * mean;
        float rs   = rsqrtf(var + 1e-5f);
        #pragma unroll
        for (int i = 0; i < 4; ++i) {
            int hh = lane + (i << 6);
            float o = (v[i] - mean) * rs * gamma[hh] + beta[hh];
            out[((size_t)b * Ln + l0 + l) * Hn + hh] = o;
        }
    }
}

// ---------------------------------------------------------------------------
extern "C" void kernel_launch(void* const* d_in, const int* in_sizes, int n_in,
                              void* d_out, int out_size, void* d_ws, size_t ws_size,
                              hipStream_t stream)
{
    const float* u     = (const float*)d_in[0];
    const float* lnr   = (const float*)d_in[1];
    const float* im    = (const float*)d_in[2];
    const float* Bre   = (const float*)d_in[3];
    const float* Bim   = (const float*)d_in[4];
    const float* Cre   = (const float*)d_in[5];
    const float* Cim   = (const float*)d_in[6];
    const float* Dp    = (const float*)d_in[7];
    const float* lstep = (const float*)d_in[8];
    const float* gam   = (const float*)d_in[9];
    const float* bet   = (const float*)d_in[10];
    float* out = (float*)d_out;

    // workspace carve (floats) — S buffer eliminated
    float* ws   = (float*)d_ws;
    float* uT   = ws;                                  // B*H*L      = 2097152
    float* G    = uT   + (size_t)Bn * Hn * Ln;         // H*64*N*2   = 2097152
    float* apar = G    + (size_t)Hn * 64 * Nn * 2;     // H*N*2      = 32768
    float* Krow = apar + (size_t)Hn * Nn * 2;          // H*64       = 16384
    float* ypre = Krow + (size_t)Hn * 64;              // B*H*L      = 2097152

    k_pre<<<768, 256, 0, stream>>>(u, uT, lnr, im, Bre, Bim, Cre, Cim, lstep, G, apar, Krow);
    k_scan_chunks<<<Bn * Hn, 256, 0, stream>>>(uT, apar, G, Krow, Dp, ypre);
    k_ln<<<dim3(Ln / 32, Bn), 256, 0, stream>>>(ypre, gam, bet, out);
}

// Round 5
// 123.557 us; speedup vs baseline: 2.8146x; 1.1070x over previous
//
#include <hip/hip_runtime.h>
#include <hip/hip_bf16.h>
#include <math.h>

// Problem constants
#define Hn 256
#define Nn 64
#define Bn 4
#define Ln 2048
#define Cn 64      // chunk length
#define NC 32      // chunks per sequence (Ln/Cn)

// ---------------------------------------------------------------------------
// K0 (merged): blocks [0,512): transpose u (B,L,H)->uT (B,H,L), 64x64 tiles,
//              float4 global loads/stores, scalar LDS (pad 65, conflict-free).
//              blocks [512,768): per-h parameter precompute (G, apar, Krow).
// ---------------------------------------------------------------------------
__global__ __launch_bounds__(256)
void k_pre(const float* __restrict__ u, float* __restrict__ uT,
           const float* __restrict__ lnr, const float* __restrict__ im,
           const float* __restrict__ Bre, const float* __restrict__ Bim,
           const float* __restrict__ Cre, const float* __restrict__ Cim,
           const float* __restrict__ lstep,
           float* __restrict__ G, float* __restrict__ apar,
           float* __restrict__ Krow)
{
    __shared__ float sh[64 * 65];
    int bid = blockIdx.x;
    int t   = threadIdx.x;

    if (bid < 512) {
        int b  = bid >> 7;
        int h0 = ((bid >> 5) & 3) << 6;
        int l0 = (bid & 31) << 6;
        int c4 = t & 15, rr = t >> 4;
        #pragma unroll
        for (int i = 0; i < 4; ++i) {
            int r = rr + (i << 4);
            float4 v = *(const float4*)&u[((size_t)b * Ln + l0 + r) * Hn + h0 + (c4 << 2)];
            sh[r * 65 + (c4 << 2) + 0] = v.x;
            sh[r * 65 + (c4 << 2) + 1] = v.y;
            sh[r * 65 + (c4 << 2) + 2] = v.z;
            sh[r * 65 + (c4 << 2) + 3] = v.w;
        }
        __syncthreads();
        #pragma unroll
        for (int i = 0; i < 4; ++i) {
            int hr = (t >> 4) + (i << 4);
            int lc = t & 15;
            float4 v;
            v.x = sh[((lc << 2) + 0) * 65 + hr];
            v.y = sh[((lc << 2) + 1) * 65 + hr];
            v.z = sh[((lc << 2) + 2) * 65 + hr];
            v.w = sh[((lc << 2) + 3) * 65 + hr];
            *(float4*)&uT[((size_t)b * Hn + h0 + hr) * Ln + l0 + (lc << 2)] = v;
        }
    } else {
        int h = bid - 512;
        int n = t;
        if (t < 64) {
            float st  = fminf(fmaxf(expf(lstep[h]), 1e-5f), 1.0f);
            float lam = -expf(lnr[n]);
            float er  = expf(st * lam);
            float sim = st * im[n];
            float ar  = er * cosf(sim);
            float ai  = er * sinf(sim);
            float bre = Bre[h * Nn + n] * st;
            float bim = Bim[h * Nn + n] * st;
            float cr  = Cre[h * Nn + n];
            float ci  = Cim[h * Nn + n];
            float CBr = cr * bre - ci * bim;
            float CBi = cr * bim + ci * bre;

            *(float2*)&apar[(h * Nn + n) * 2] = make_float2(ar, ai);

            float Pr = ar, Pi = ai;   // a^(j+1)
            float Qr = 1.f, Qi = 0.f; // a^j
            for (int j = 0; j < 64; ++j) {
                *(float2*)&G[((h * 64 + j) * 64 + n) * 2] =
                    make_float2(CBr * Pr - CBi * Pi, CBr * Pi + CBi * Pr);
                sh[j * 65 + n] = CBr * Qr - CBi * Qi;
                float npr = Pr * ar - Pi * ai; Pi = Pr * ai + Pi * ar; Pr = npr;
                float nqr = Qr * ar - Qi * ai; Qi = Qr * ai + Qi * ar; Qr = nqr;
            }
        }
        __syncthreads();
        if (t < 64) {
            float s = 0.f;
            #pragma unroll
            for (int m = 0; m < 64; ++m) s += sh[t * 65 + m];
            Krow[h * 64 + t] = s;
        }
    }
}

// ---------------------------------------------------------------------------
// K1 (fused scan+chunks, v3). block = (b,h), 4 waves x 64 lanes.
//  Phase 1 (lane=n): wave w scans segment [512w,512w+512) from zero, float4 u
//    loads; local chunk states in regs; segment-final F_w -> LDS.
//  Combine: X_{s+1} = a^512 X_s + F_s; true S[8w+k] = Sloc[k] + a^{64k} X_w.
//  Phase 2 (lane=j): wave w owns n,m-slice [16w,16w+16); S via ds_read_b128,
//    conv-u via float4 (L1-resident); partials in 16-chunk halves -> LDS
//    (34.5 KB total -> 4 blocks/CU, no tail) -> reduce + D*u + exact GELU.
// ---------------------------------------------------------------------------
__global__ __launch_bounds__(256, 4)
void k_scan_chunks(const float* __restrict__ uT, const float* __restrict__ apar,
                   const float* __restrict__ G, const float* __restrict__ Krow,
                   const float* __restrict__ D, float* __restrict__ ypre)
{
    int bh  = blockIdx.x;
    int h   = bh & (Hn - 1);
    int tid = threadIdx.x;
    int j   = tid & 63;
    int w   = __builtin_amdgcn_readfirstlane(tid >> 6);
    int n0  = w << 4;

    __shared__ float  kbuf[128];          // 0.5 KB zero-padded Krow
    __shared__ float2 S_lds[NC][64];      // 16 KB true chunk states
    __shared__ float2 F_lds[4][64];       // 2 KB segment finals
    __shared__ float  part[16][4][64];    // 16 KB half-batch partials

    if (tid < 64) kbuf[tid] = 0.f;
    else if (tid < 128) kbuf[tid] = Krow[h * 64 + tid - 64];

    // ---- phase 1: segmented scan (lane = n) ----
    int n = j;
    float ar = apar[(h * Nn + n) * 2];
    float ai = apar[(h * Nn + n) * 2 + 1];
    float a2r = ar * ar - ai * ai;
    float a2i = 2.f * ar * ai;
    const float* uRow = uT + (size_t)bh * Ln;
    const float* useg = uRow + (w << 9);

    float2 Sloc[8];
    float xr = 0.f, xi = 0.f;
    #pragma unroll
    for (int k = 0; k < 8; ++k) {
        Sloc[k] = make_float2(xr, xi);
        const float4* up4 = (const float4*)(useg + (k << 6));
        #pragma unroll
        for (int q = 0; q < 16; ++q) {
            float4 uu = up4[q];
            float crr = fmaf(ar, uu.x, uu.y);
            float cii = ai * uu.x;
            float nxr = fmaf(a2r, xr, fmaf(-a2i, xi, crr));
            float nxi = fmaf(a2i, xr, fmaf(a2r, xi, cii));
            xr = nxr; xi = nxi;
            crr = fmaf(ar, uu.z, uu.w);
            cii = ai * uu.z;
            nxr = fmaf(a2r, xr, fmaf(-a2i, xi, crr));
            nxi = fmaf(a2i, xr, fmaf(a2r, xi, cii));
            xr = nxr; xi = nxi;
        }
    }
    F_lds[w][n] = make_float2(xr, xi);
    __syncthreads();

    // a^64 (6 squarings), p = a^512 (3 more)
    float b_r = ar, b_i = ai;
    #pragma unroll
    for (int q = 0; q < 6; ++q) { float nr = b_r * b_r - b_i * b_i; b_i = 2.f * b_r * b_i; b_r = nr; }
    float p_r = b_r, p_i = b_i;
    #pragma unroll
    for (int q = 0; q < 3; ++q) { float nr = p_r * p_r - p_i * p_i; p_i = 2.f * p_r * p_i; p_r = nr; }

    // X_w = fold_{s<w} (X = p*X + F_s)
    float Xr = 0.f, Xi = 0.f;
    for (int s = 0; s < w; ++s) {
        float2 Ft = F_lds[s][n];
        float nXr = fmaf(p_r, Xr, fmaf(-p_i, Xi, Ft.x));
        float nXi = fmaf(p_i, Xr, fmaf(p_r, Xi, Ft.y));
        Xr = nXr; Xi = nXi;
    }

    // true states: S[8w+k] = Sloc[k] + a^{64k} * X
    float e_r = 1.f, e_i = 0.f;
    #pragma unroll
    for (int k = 0; k < 8; ++k) {
        float sr = Sloc[k].x + (e_r * Xr - e_i * Xi);
        float si = Sloc[k].y + (e_r * Xi + e_i * Xr);
        S_lds[(w << 3) + k][n] = make_float2(sr, si);
        float nr = e_r * b_r - e_i * b_i;
        e_i = e_r * b_i + e_i * b_r;
        e_r = nr;
    }
    __syncthreads();

    // ---- phase 2 (lane = j) ----
    float4 Gr4[8];   // 16 float2: {re,im,re,im} pairs
    const float4* Gp4 = (const float4*)((const float2*)G + ((h * 64 + j) * 64 + n0));
    #pragma unroll
    for (int i = 0; i < 8; ++i) Gr4[i] = Gp4[i];
    float Kreg[16];
    #pragma unroll
    for (int i = 0; i < 16; ++i) Kreg[i] = kbuf[64 + j - n0 - i];

    float Dh = D[h];

    for (int half = 0; half < 2; ++half) {
        for (int cc = 0; cc < 16; ++cc) {
            int c = (half << 4) | cc;
            const float4* Sp4 = (const float4*)&S_lds[c][n0];   // broadcast b128
            const float4* uc4 = (const float4*)(uRow + (c << 6) + n0);
            float y0 = 0.f, y1 = 0.f, y2 = 0.f;
            #pragma unroll
            for (int i = 0; i < 8; ++i) {
                float4 sv = Sp4[i];
                y0 = fmaf(Gr4[i].x, sv.x, y0);
                y1 = fmaf(-Gr4[i].y, sv.y, y1);
                y0 = fmaf(Gr4[i].z, sv.z, y0);
                y1 = fmaf(-Gr4[i].w, sv.w, y1);
            }
            #pragma unroll
            for (int i = 0; i < 4; ++i) {
                float4 uu = uc4[i];
                y2 = fmaf(Kreg[4 * i + 0], uu.x, y2);
                y2 = fmaf(Kreg[4 * i + 1], uu.y, y2);
                y2 = fmaf(Kreg[4 * i + 2], uu.z, y2);
                y2 = fmaf(Kreg[4 * i + 3], uu.w, y2);
            }
            part[cc][w][j] = (y0 + y1) + y2;
        }
        __syncthreads();
        #pragma unroll
        for (int k = 0; k < 4; ++k) {
            int cc = (k << 2) | w;
            int c  = (half << 4) | cc;
            float y  = (part[cc][0][j] + part[cc][1][j]) + (part[cc][2][j] + part[cc][3][j]);
            float uv = uRow[(c << 6) + j];
            float yv = fmaf(Dh, uv, y);
            float g  = 0.5f * yv * (1.f + erff(yv * 0.70710678118654752f));
            ypre[(size_t)bh * Ln + (c << 6) + j] = g;
        }
        __syncthreads();
    }
}

// ---------------------------------------------------------------------------
// K2: LayerNorm over H; float4 global I/O, transposed LDS tile [l][h] pad 4.
// grid: (64 ltiles, 4 b) x 256 threads.
// ---------------------------------------------------------------------------
__global__ __launch_bounds__(256)
void k_ln(const float* __restrict__ ypre, const float* __restrict__ gamma,
          const float* __restrict__ beta, float* __restrict__ out)
{
    __shared__ float tile[32][260];   // rows 1040 B -> 16B-aligned for b128 reads
    int b  = blockIdx.y;
    int l0 = blockIdx.x << 5;
    int t  = threadIdx.x;

    // stage 32 l x 256 h: thread reads float4 along l
    #pragma unroll
    for (int i = 0; i < 8; ++i) {
        int idx = (i << 8) + t;          // 0..2047
        int hh  = idx >> 3, lo4 = idx & 7;
        float4 v = *(const float4*)&ypre[((size_t)b * Hn + hh) * Ln + l0 + (lo4 << 2)];
        tile[(lo4 << 2) + 0][hh] = v.x;
        tile[(lo4 << 2) + 1][hh] = v.y;
        tile[(lo4 << 2) + 2][hh] = v.z;
        tile[(lo4 << 2) + 3][hh] = v.w;
    }
    __syncthreads();

    int wv = t >> 6, lane = t & 63;
    float4 g4 = *(const float4*)&gamma[lane << 2];
    float4 b4 = *(const float4*)&beta[lane << 2];
    #pragma unroll
    for (int k = 0; k < 8; ++k) {
        int l = (k << 2) | wv;
        float4 v = *(const float4*)&tile[l][lane << 2];
        float sum = (v.x + v.y) + (v.z + v.w);
        float sq  = fmaf(v.x, v.x, fmaf(v.y, v.y, fmaf(v.z, v.z, v.w * v.w)));
        #pragma unroll
        for (int off = 32; off; off >>= 1) {
            sum += __shfl_xor(sum, off);
            sq  += __shfl_xor(sq, off);
        }
        float mean = sum * (1.f / 256.f);
        float var  = sq * (1.f / 256.f) - mean * mean;
        float rs   = rsqrtf(var + 1e-5f);
        float4 o;
        o.x = (v.x - mean) * rs * g4.x + b4.x;
        o.y = (v.y - mean) * rs * g4.y + b4.y;
        o.z = (v.z - mean) * rs * g4.z + b4.z;
        o.w = (v.w - mean) * rs * g4.w + b4.w;
        *(float4*)&out[((size_t)b * Ln + l0 + l) * Hn + (lane << 2)] = o;
    }
}

// ---------------------------------------------------------------------------
extern "C" void kernel_launch(void* const* d_in, const int* in_sizes, int n_in,
                              void* d_out, int out_size, void* d_ws, size_t ws_size,
                              hipStream_t stream)
{
    const float* u     = (const float*)d_in[0];
    const float* lnr   = (const float*)d_in[1];
    const float* im    = (const float*)d_in[2];
    const float* Bre   = (const float*)d_in[3];
    const float* Bim   = (const float*)d_in[4];
    const float* Cre   = (const float*)d_in[5];
    const float* Cim   = (const float*)d_in[6];
    const float* Dp    = (const float*)d_in[7];
    const float* lstep = (const float*)d_in[8];
    const float* gam   = (const float*)d_in[9];
    const float* bet   = (const float*)d_in[10];
    float* out = (float*)d_out;

    // workspace carve (floats)
    float* ws   = (float*)d_ws;
    float* uT   = ws;                                  // B*H*L      = 2097152
    float* G    = uT   + (size_t)Bn * Hn * Ln;         // H*64*N*2   = 2097152
    float* apar = G    + (size_t)Hn * 64 * Nn * 2;     // H*N*2      = 32768
    float* Krow = apar + (size_t)Hn * Nn * 2;          // H*64       = 16384
    float* ypre = Krow + (size_t)Hn * 64;              // B*H*L      = 2097152

    k_pre<<<768, 256, 0, stream>>>(u, uT, lnr, im, Bre, Bim, Cre, Cim, lstep, G, apar, Krow);
    k_scan_chunks<<<Bn * Hn, 256, 0, stream>>>(uT, apar, G, Krow, Dp, ypre);
    k_ln<<<dim3(Ln / 32, Bn), 256, 0, stream>>>(ypre, gam, bet, out);
}

// Round 7
// 106.370 us; speedup vs baseline: 3.2694x; 1.1616x over previous
//
#include <hip/hip_runtime.h>
#include <hip/hip_bf16.h>
#include <math.h>

// Problem constants
#define Hn 256
#define Nn 64
#define Bn 4
#define Ln 2048
#define NC 32      // chunks per sequence

typedef __attribute__((ext_vector_type(8))) short short8;
typedef __attribute__((ext_vector_type(4))) float f32x4;

#define MFMA16 __builtin_amdgcn_mfma_f32_16x16x32_bf16

// AF1: per h, 32 slots x 512 shorts = 16384 shorts (64x64 re/im x hi/lo)
#define AF1_STRIDE 16384
// AF2: per h, 48 slots x 512 shorts = 24576 shorts (64x192 hi/lo)
#define AF2_STRIDE 24576

__device__ inline short bf16hi(float x) {
    union { __hip_bfloat16 b; unsigned short u; } cv;
    cv.b = __float2bfloat16(x);
    return (short)cv.u;
}
__device__ inline float bf16f(short s) {
    union { __hip_bfloat16 b; unsigned short u; } cv;
    cv.u = (unsigned short)s;
    return __bfloat162float(cv.b);
}

// complex square in place
#define CSQ(r, i) { float _nr = (r)*(r) - (i)*(i); (i) = 2.f*(r)*(i); (r) = _nr; }

// ---------------------------------------------------------------------------
// K0: blocks [0,512): transpose u (B,L,H)->uT (B,H,L), float4 both ways.
//     blocks [512,768): per-h precompute, emitting MFMA A-fragments:
//       AF1[h]: Apow (re,im) hi/lo — A1[n][t] = a_n^{63-t}, 64x64
//       AF2[h]: [T | Gre | -Gim] hi/lo — 64x192
//       apar[h][n] = a_n^64 (complex)
//     Fragment layout (16x16x32 bf16 A-op): lane holds A[m=lane&15][k=quad*8+j]
//     stored [..][mt][kt][lane][j] so k_scan_chunks reads short8 at lane*8.
// ---------------------------------------------------------------------------
__global__ __launch_bounds__(256)
void k_pre(const float* __restrict__ u, float* __restrict__ uT,
           const float* __restrict__ lnr, const float* __restrict__ im,
           const float* __restrict__ Bre, const float* __restrict__ Bim,
           const float* __restrict__ Cre, const float* __restrict__ Cim,
           const float* __restrict__ lstep,
           short* __restrict__ AF1, short* __restrict__ AF2,
           float* __restrict__ apar)
{
    __shared__ float sh[2][64][66];
    __shared__ float cbrL[64];
    __shared__ float kb[128];
    int bid = blockIdx.x;
    int tid = threadIdx.x;

    if (bid < 512) {
        // ---- transpose tile ----
        int b  = bid >> 7;
        int h0 = ((bid >> 5) & 3) << 6;
        int l0 = (bid & 31) << 6;
        int c4 = tid & 15, rr = tid >> 4;
        #pragma unroll
        for (int i = 0; i < 4; ++i) {
            int r = rr + (i << 4);
            float4 v = *(const float4*)&u[((size_t)b * Ln + l0 + r) * Hn + h0 + (c4 << 2)];
            sh[0][r][(c4 << 2) + 0] = v.x;
            sh[0][r][(c4 << 2) + 1] = v.y;
            sh[0][r][(c4 << 2) + 2] = v.z;
            sh[0][r][(c4 << 2) + 3] = v.w;
        }
        __syncthreads();
        #pragma unroll
        for (int i = 0; i < 4; ++i) {
            int hr = (tid >> 4) + (i << 4);
            int lc = tid & 15;
            float4 v;
            v.x = sh[0][(lc << 2) + 0][hr];
            v.y = sh[0][(lc << 2) + 1][hr];
            v.z = sh[0][(lc << 2) + 2][hr];
            v.w = sh[0][(lc << 2) + 3][hr];
            *(float4*)&uT[((size_t)b * Hn + h0 + hr) * Ln + l0 + (lc << 2)] = v;
        }
        return;
    }

    // ---- per-h precompute ----
    int h    = bid - 512;
    int lane = tid & 63;
    int wv   = tid >> 6;
    int kq   = lane >> 4;
    int l15  = lane & 15;
    int mrow = (wv << 4) + l15;

    // per-lane (n = lane) parameters — every wave recomputes (cheap)
    float st  = fminf(fmaxf(expf(lstep[h]), 1e-5f), 1.0f);
    float lam = -expf(lnr[lane]);
    float er  = expf(st * lam);
    float smv = st * im[lane];
    float ar  = er * cosf(smv);
    float ai  = er * sinf(smv);
    float bre = Bre[h * Nn + lane] * st;
    float bim = Bim[h * Nn + lane] * st;
    float crr = Cre[h * Nn + lane];
    float cii = Cim[h * Nn + lane];
    float cbr = crr * bre - cii * bim;
    float cbi = crr * bim + cii * bre;

    // power ladder: a^16, a^32, a^48, a^64
    float a16r = ar, a16i = ai;
    CSQ(a16r, a16i); CSQ(a16r, a16i); CSQ(a16r, a16i); CSQ(a16r, a16i);
    float a32r = a16r, a32i = a16i; CSQ(a32r, a32i);
    float a48r = a32r * a16r - a32i * a16i;
    float a48i = a32r * a16i + a32i * a16r;
    float a64r = a32r, a64i = a32i; CSQ(a64r, a64i);
    if (tid < 64) {
        apar[(h * Nn + lane) * 2]     = a64r;
        apar[(h * Nn + lane) * 2 + 1] = a64i;
    }

    // stage A: Apow[n][t] = a^(63-t); wave wv covers powers 16*wv .. 16*wv+15
    float pr = 1.f, pi = 0.f;
    if (wv == 1) { pr = a16r; pi = a16i; }
    else if (wv == 2) { pr = a32r; pi = a32i; }
    else if (wv == 3) { pr = a48r; pi = a48i; }
    for (int i = 0; i < 16; ++i) {
        int t = 63 - ((wv << 4) + i);
        sh[0][lane][t] = pr;
        sh[1][lane][t] = pi;
        float nr = pr * ar - pi * ai; pi = pr * ai + pi * ar; pr = nr;
    }
    __syncthreads();

    // AF1 fragment stores
    short* A1h = AF1 + (size_t)h * AF1_STRIDE;
    #pragma unroll
    for (int cm = 0; cm < 2; ++cm)
        #pragma unroll
        for (int kt = 0; kt < 2; ++kt) {
            union { short s[8]; short8 v; } uh, ul;
            #pragma unroll
            for (int j = 0; j < 8; ++j) {
                float x = sh[cm][mrow][kt * 32 + kq * 8 + j];
                short hh = bf16hi(x);
                uh.s[j] = hh;
                ul.s[j] = bf16hi(x - bf16f(hh));
            }
            *(short8*)&A1h[(((cm * 2 + 0) * 4 + wv) * 2 + kt) * 512 + lane * 8] = uh.v;
            *(short8*)&A1h[(((cm * 2 + 1) * 4 + wv) * 2 + kt) * 512 + lane * 8] = ul.v;
        }
    __syncthreads();

    // stage B: Gre/Gim into sh (G[j][n] = CB * a^(j+1))
    if (tid < 64) {
        cbrL[lane] = cbr;
        float Pr = ar, Pi = ai;
        for (int j = 0; j < 64; ++j) {
            sh[0][j][lane] = cbr * Pr - cbi * Pi;
            sh[1][j][lane] = cbr * Pi + cbi * Pr;
            float nr = Pr * ar - Pi * ai; Pi = Pr * ai + Pi * ar; Pr = nr;
        }
    }
    __syncthreads();
    // Krow -> kb (zero-padded low half): Krow[t] = sum_n Re(CB_n a_n^t)
    if (tid < 64) kb[tid] = 0.f;
    else if (tid < 128) {
        int t2 = tid - 64;
        float s = 0.f;
        if (t2 == 0) { for (int n2 = 0; n2 < 64; ++n2) s += cbrL[n2]; }
        else         { for (int n2 = 0; n2 < 64; ++n2) s += sh[0][t2 - 1][n2]; }
        kb[tid] = s;
    }
    __syncthreads();

    // AF2 fragment stores: A2 = [T | Gre | -Gim], 64x192
    short* A2h = AF2 + (size_t)h * AF2_STRIDE;
    #pragma unroll
    for (int kt = 0; kt < 6; ++kt) {
        union { short s[8]; short8 v; } uh, ul;
        #pragma unroll
        for (int j = 0; j < 8; ++j) {
            float x;
            if (kt < 2) {
                int kk = kt * 32 + kq * 8 + j;          // m index of T
                x = kb[64 + mrow - kk];                  // T[j][m] = Krow[j-m]
            } else {
                int q2 = kt - 2;
                int nn = (q2 & 1) * 32 + kq * 8 + j;
                x = (q2 >> 1) ? -sh[1][mrow][nn] : sh[0][mrow][nn];
            }
            short hh = bf16hi(x);
            uh.s[j] = hh;
            ul.s[j] = bf16hi(x - bf16f(hh));
        }
        *(short8*)&A2h[((0 * 4 + wv) * 6 + kt) * 512 + lane * 8] = uh.v;
        *(short8*)&A2h[((1 * 4 + wv) * 6 + kt) * 512 + lane * 8] = ul.v;
    }
}

// ---------------------------------------------------------------------------
// K1 (MFMA scan+chunks). block = (b,h), 4 waves; wave w owns m-tile w.
//  set1: P(64n x 32c) = Apow(64x64) * U(64t x 32c)   [bf16 hi/lo, 3-term]
//  scan: S[c] = a64*S[c-1] + P[c-1] (32 steps, lane = n, waves duplicate,
//        wave w stages bf16 hi/lo S for its c-range into Sb)
//  set2: Y(64j x 32c) = [T|Gre|-Gim](64x192) * [U;Sre;Sim](192x32)
//  epilogue: Y + D*u -> exact GELU -> ypre[b,h,l]
// ---------------------------------------------------------------------------
__global__ __launch_bounds__(256, 4)
void k_scan_chunks(const float* __restrict__ uT, const float* __restrict__ apar,
                   const short* __restrict__ AF1, const short* __restrict__ AF2,
                   const float* __restrict__ D, float* __restrict__ ypre)
{
    __shared__ float P2[64][35][2];        // P (re,im) fp32; aliased as Y later
    __shared__ short Sb[2][2][32][72];     // [split][reim][c][n]

    int bh   = blockIdx.x;
    int h    = bh & (Hn - 1);
    int tid  = threadIdx.x;
    int lane = tid & 63;
    int w    = __builtin_amdgcn_readfirstlane(tid >> 6);
    int l15  = lane & 15;
    int kq   = lane >> 4;

    const float* uRow = uT + (size_t)bh * Ln;
    const short* A1h  = AF1 + (size_t)h * AF1_STRIDE;
    const short* A2h  = AF2 + (size_t)h * AF2_STRIDE;

    // ---- U fragments direct from global (L1), bf16 hi/lo ----
    short8 Uh[2][2], Ul[2][2];             // [kt][ct]
    #pragma unroll
    for (int kt = 0; kt < 2; ++kt)
        #pragma unroll
        for (int ct = 0; ct < 2; ++ct) {
            int c = ct * 16 + l15;
            const float* up = uRow + c * 64 + kt * 32 + kq * 8;
            float4 f0 = *(const float4*)up;
            float4 f1 = *(const float4*)(up + 4);
            float xv[8] = {f0.x, f0.y, f0.z, f0.w, f1.x, f1.y, f1.z, f1.w};
            union { short s[8]; short8 v; } hh, ll;
            #pragma unroll
            for (int j = 0; j < 8; ++j) {
                short hs = bf16hi(xv[j]);
                hh.s[j] = hs;
                ll.s[j] = bf16hi(xv[j] - bf16f(hs));
            }
            Uh[kt][ct] = hh.v;
            Ul[kt][ct] = ll.v;
        }

    // ---- set 1: P = Apow * U ----
    f32x4 Pre_acc[2] = {{0.f,0.f,0.f,0.f},{0.f,0.f,0.f,0.f}};
    f32x4 Pim_acc[2] = {{0.f,0.f,0.f,0.f},{0.f,0.f,0.f,0.f}};
    #pragma unroll
    for (int kt = 0; kt < 2; ++kt) {
        short8 a_re_h = *(const short8*)&A1h[((0 * 4 + w) * 2 + kt) * 512 + lane * 8];
        short8 a_re_l = *(const short8*)&A1h[((1 * 4 + w) * 2 + kt) * 512 + lane * 8];
        short8 a_im_h = *(const short8*)&A1h[((2 * 4 + w) * 2 + kt) * 512 + lane * 8];
        short8 a_im_l = *(const short8*)&A1h[((3 * 4 + w) * 2 + kt) * 512 + lane * 8];
        #pragma unroll
        for (int ct = 0; ct < 2; ++ct) {
            Pre_acc[ct] = MFMA16(a_re_h, Uh[kt][ct], Pre_acc[ct], 0, 0, 0);
            Pre_acc[ct] = MFMA16(a_re_h, Ul[kt][ct], Pre_acc[ct], 0, 0, 0);
            Pre_acc[ct] = MFMA16(a_re_l, Uh[kt][ct], Pre_acc[ct], 0, 0, 0);
            Pim_acc[ct] = MFMA16(a_im_h, Uh[kt][ct], Pim_acc[ct], 0, 0, 0);
            Pim_acc[ct] = MFMA16(a_im_h, Ul[kt][ct], Pim_acc[ct], 0, 0, 0);
            Pim_acc[ct] = MFMA16(a_im_l, Uh[kt][ct], Pim_acc[ct], 0, 0, 0);
        }
    }
    // P -> LDS (C/D layout: col = lane&15, row = quad*4 + reg)
    #pragma unroll
    for (int ct = 0; ct < 2; ++ct)
        #pragma unroll
        for (int r = 0; r < 4; ++r) {
            int n = (w << 4) + kq * 4 + r;
            int c = ct * 16 + l15;
            *(float2*)&P2[n][c][0] = make_float2(Pre_acc[ct][r], Pim_acc[ct][r]);
        }
    __syncthreads();

    // ---- scan (lane = n); every wave duplicates, wave w stages its c-range ----
    {
        int n = lane;
        float a64r = apar[(h * Nn + n) * 2];
        float a64i = apar[(h * Nn + n) * 2 + 1];
        float sr = 0.f, si = 0.f;
        for (int c = 0; c < NC; ++c) {
            if ((c >> 3) == w) {
                short hr = bf16hi(sr); short lr = bf16hi(sr - bf16f(hr));
                short hi2 = bf16hi(si); short li = bf16hi(si - bf16f(hi2));
                Sb[0][0][c][n] = hr;  Sb[1][0][c][n] = lr;
                Sb[0][1][c][n] = hi2; Sb[1][1][c][n] = li;
            }
            float2 pv = *(float2*)&P2[n][c][0];
            float nsr = fmaf(a64r, sr, fmaf(-a64i, si, pv.x));
            float nsi = fmaf(a64i, sr, fmaf(a64r, si, pv.y));
            sr = nsr; si = nsi;
        }
    }
    __syncthreads();

    // ---- set 2: Y = [T|Gre|-Gim] * [U;Sre;Sim] ----
    f32x4 Yacc[2] = {{0.f,0.f,0.f,0.f},{0.f,0.f,0.f,0.f}};
    #pragma unroll
    for (int kt = 0; kt < 6; ++kt) {
        short8 a_h = *(const short8*)&A2h[((0 * 4 + w) * 6 + kt) * 512 + lane * 8];
        short8 a_l = *(const short8*)&A2h[((1 * 4 + w) * 6 + kt) * 512 + lane * 8];
        #pragma unroll
        for (int ct = 0; ct < 2; ++ct) {
            short8 bhf, blf;
            if (kt < 2) { bhf = Uh[kt][ct]; blf = Ul[kt][ct]; }
            else {
                int q2 = kt - 2, reim = q2 >> 1;
                int nb = (q2 & 1) * 32 + kq * 8;
                int c  = ct * 16 + l15;
                bhf = *(const short8*)&Sb[0][reim][c][nb];
                blf = *(const short8*)&Sb[1][reim][c][nb];
            }
            Yacc[ct] = MFMA16(a_h, bhf, Yacc[ct], 0, 0, 0);
            Yacc[ct] = MFMA16(a_h, blf, Yacc[ct], 0, 0, 0);
            Yacc[ct] = MFMA16(a_l, bhf, Yacc[ct], 0, 0, 0);
        }
    }
    // Y -> LDS (reuse P2 region, stride 70 floats)
    float* Yl = (float*)P2;
    #pragma unroll
    for (int ct = 0; ct < 2; ++ct)
        #pragma unroll
        for (int r = 0; r < 4; ++r) {
            int j = (w << 4) + kq * 4 + r;
            int c = ct * 16 + l15;
            Yl[j * 70 + c] = Yacc[ct][r];
        }
    __syncthreads();

    // ---- epilogue: +D*u, exact GELU, coalesced store ----
    float Dh = D[h];
    #pragma unroll
    for (int i = 0; i < 8; ++i) {
        int c = (w << 3) + i;
        float y  = Yl[lane * 70 + c];
        float uv = uRow[c * 64 + lane];
        float yv = fmaf(Dh, uv, y);
        float g  = 0.5f * yv * (1.f + erff(yv * 0.70710678118654752f));
        ypre[(size_t)bh * Ln + c * 64 + lane] = g;
    }
}

// ---------------------------------------------------------------------------
// K2: LayerNorm over H; float4 global I/O, transposed LDS tile.
// ---------------------------------------------------------------------------
__global__ __launch_bounds__(256)
void k_ln(const float* __restrict__ ypre, const float* __restrict__ gamma,
          const float* __restrict__ beta, float* __restrict__ out)
{
    __shared__ float tile[32][260];
    int b  = blockIdx.y;
    int l0 = blockIdx.x << 5;
    int t  = threadIdx.x;

    #pragma unroll
    for (int i = 0; i < 8; ++i) {
        int idx = (i << 8) + t;
        int hh  = idx >> 3, lo4 = idx & 7;
        float4 v = *(const float4*)&ypre[((size_t)b * Hn + hh) * Ln + l0 + (lo4 << 2)];
        tile[(lo4 << 2) + 0][hh] = v.x;
        tile[(lo4 << 2) + 1][hh] = v.y;
        tile[(lo4 << 2) + 2][hh] = v.z;
        tile[(lo4 << 2) + 3][hh] = v.w;
    }
    __syncthreads();

    int wv = t >> 6, lane = t & 63;
    float4 g4 = *(const float4*)&gamma[lane << 2];
    float4 b4 = *(const float4*)&beta[lane << 2];
    #pragma unroll
    for (int k = 0; k < 8; ++k) {
        int l = (k << 2) | wv;
        float4 v = *(const float4*)&tile[l][lane << 2];
        float sum = (v.x + v.y) + (v.z + v.w);
        float sq  = fmaf(v.x, v.x, fmaf(v.y, v.y, fmaf(v.z, v.z, v.w * v.w)));
        #pragma unroll
        for (int off = 32; off; off >>= 1) {
            sum += __shfl_xor(sum, off);
            sq  += __shfl_xor(sq, off);
        }
        float mean = sum * (1.f / 256.f);
        float var  = sq * (1.f / 256.f) - mean * mean;
        float rs   = rsqrtf(var + 1e-5f);
        float4 o;
        o.x = (v.x - mean) * rs * g4.x + b4.x;
        o.y = (v.y - mean) * rs * g4.y + b4.y;
        o.z = (v.z - mean) * rs * g4.z + b4.z;
        o.w = (v.w - mean) * rs * g4.w + b4.w;
        *(float4*)&out[((size_t)b * Ln + l0 + l) * Hn + (lane << 2)] = o;
    }
}

// ---------------------------------------------------------------------------
extern "C" void kernel_launch(void* const* d_in, const int* in_sizes, int n_in,
                              void* d_out, int out_size, void* d_ws, size_t ws_size,
                              hipStream_t stream)
{
    const float* u     = (const float*)d_in[0];
    const float* lnr   = (const float*)d_in[1];
    const float* im    = (const float*)d_in[2];
    const float* Bre   = (const float*)d_in[3];
    const float* Bim   = (const float*)d_in[4];
    const float* Cre   = (const float*)d_in[5];
    const float* Cim   = (const float*)d_in[6];
    const float* Dp    = (const float*)d_in[7];
    const float* lstep = (const float*)d_in[8];
    const float* gam   = (const float*)d_in[9];
    const float* bet   = (const float*)d_in[10];
    float* out = (float*)d_out;

    // workspace carve
    float* ws   = (float*)d_ws;
    float* uT   = ws;                                   // 2,097,152 f
    float* apar = uT + (size_t)Bn * Hn * Ln;            //    32,768 f
    float* ypre = apar + (size_t)Hn * Nn * 2;           // 2,097,152 f
    short* AF1  = (short*)(ypre + (size_t)Bn * Hn * Ln);// Hn*16384 sh (16B-aligned)
    short* AF2  = AF1 + (size_t)Hn * AF1_STRIDE;        // Hn*24576 sh

    k_pre<<<768, 256, 0, stream>>>(u, uT, lnr, im, Bre, Bim, Cre, Cim, lstep, AF1, AF2, apar);
    k_scan_chunks<<<Bn * Hn, 256, 0, stream>>>(uT, apar, AF1, AF2, Dp, ypre);
    k_ln<<<dim3(Ln / 32, Bn), 256, 0, stream>>>(ypre, gam, bet, out);
}

// Round 8
// 103.688 us; speedup vs baseline: 3.3540x; 1.0259x over previous
//
#include <hip/hip_runtime.h>
#include <hip/hip_bf16.h>
#include <math.h>

// Problem constants
#define Hn 256
#define Nn 64
#define Bn 4
#define Ln 2048
#define NC 32      // chunks per sequence

typedef __attribute__((ext_vector_type(8))) short short8;
typedef __attribute__((ext_vector_type(4))) float f32x4;

#define MFMA16 __builtin_amdgcn_mfma_f32_16x16x32_bf16

// AF1: per h, 16 slots x 512 shorts = 8192 shorts (64x64 re/im, bf16-hi only)
#define AF1_STRIDE 8192
// AF2: per h, 24 slots x 512 shorts = 12288 shorts (64x192, bf16-hi only)
#define AF2_STRIDE 12288

__device__ inline short bf16hi(float x) {
    union { __hip_bfloat16 b; unsigned short u; } cv;
    cv.b = __float2bfloat16(x);
    return (short)cv.u;
}
__device__ inline float bf16f(short s) {
    union { __hip_bfloat16 b; unsigned short u; } cv;
    cv.u = (unsigned short)s;
    return __bfloat162float(cv.b);
}

// complex square in place
#define CSQ(r, i) { float _nr = (r)*(r) - (i)*(i); (i) = 2.f*(r)*(i); (r) = _nr; }

// ---------------------------------------------------------------------------
// K0: blocks [0,512): transpose u (B,L,H)->uT (B,H,L), float4 both ways.
//     blocks [512,768): per-h precompute, emitting MFMA A-fragments (bf16-hi):
//       AF1[h]: Apow (re,im) — A1[n][t] = a_n^{63-t}, 64x64
//       AF2[h]: [T | Gre | -Gim] — 64x192
//       apar[h][n] = a_n^64 (complex)
//     Fragment layout (16x16x32 bf16 A-op): lane holds A[m=lane&15][k=quad*8+j]
//     stored [..][mt][kt][lane][j] so k_scan_chunks reads short8 at lane*8.
// ---------------------------------------------------------------------------
__global__ __launch_bounds__(256)
void k_pre(const float* __restrict__ u, float* __restrict__ uT,
           const float* __restrict__ lnr, const float* __restrict__ im,
           const float* __restrict__ Bre, const float* __restrict__ Bim,
           const float* __restrict__ Cre, const float* __restrict__ Cim,
           const float* __restrict__ lstep,
           short* __restrict__ AF1, short* __restrict__ AF2,
           float* __restrict__ apar)
{
    __shared__ float sh[2][64][66];
    __shared__ float cbrL[64];
    __shared__ float kb[128];
    int bid = blockIdx.x;
    int tid = threadIdx.x;

    if (bid < 512) {
        // ---- transpose tile ----
        int b  = bid >> 7;
        int h0 = ((bid >> 5) & 3) << 6;
        int l0 = (bid & 31) << 6;
        int c4 = tid & 15, rr = tid >> 4;
        #pragma unroll
        for (int i = 0; i < 4; ++i) {
            int r = rr + (i << 4);
            float4 v = *(const float4*)&u[((size_t)b * Ln + l0 + r) * Hn + h0 + (c4 << 2)];
            sh[0][r][(c4 << 2) + 0] = v.x;
            sh[0][r][(c4 << 2) + 1] = v.y;
            sh[0][r][(c4 << 2) + 2] = v.z;
            sh[0][r][(c4 << 2) + 3] = v.w;
        }
        __syncthreads();
        #pragma unroll
        for (int i = 0; i < 4; ++i) {
            int hr = (tid >> 4) + (i << 4);
            int lc = tid & 15;
            float4 v;
            v.x = sh[0][(lc << 2) + 0][hr];
            v.y = sh[0][(lc << 2) + 1][hr];
            v.z = sh[0][(lc << 2) + 2][hr];
            v.w = sh[0][(lc << 2) + 3][hr];
            *(float4*)&uT[((size_t)b * Hn + h0 + hr) * Ln + l0 + (lc << 2)] = v;
        }
        return;
    }

    // ---- per-h precompute ----
    int h    = bid - 512;
    int lane = tid & 63;
    int wv   = tid >> 6;
    int kq   = lane >> 4;
    int l15  = lane & 15;
    int mrow = (wv << 4) + l15;

    // per-lane (n = lane) parameters — every wave recomputes (cheap)
    float st  = fminf(fmaxf(expf(lstep[h]), 1e-5f), 1.0f);
    float lam = -expf(lnr[lane]);
    float er  = expf(st * lam);
    float smv = st * im[lane];
    float ar  = er * cosf(smv);
    float ai  = er * sinf(smv);
    float bre = Bre[h * Nn + lane] * st;
    float bim = Bim[h * Nn + lane] * st;
    float crr = Cre[h * Nn + lane];
    float cii = Cim[h * Nn + lane];
    float cbr = crr * bre - cii * bim;
    float cbi = crr * bim + cii * bre;

    // power ladder: a^16, a^32, a^48, a^64
    float a16r = ar, a16i = ai;
    CSQ(a16r, a16i); CSQ(a16r, a16i); CSQ(a16r, a16i); CSQ(a16r, a16i);
    float a32r = a16r, a32i = a16i; CSQ(a32r, a32i);
    float a48r = a32r * a16r - a32i * a16i;
    float a48i = a32r * a16i + a32i * a16r;
    float a64r = a32r, a64i = a32i; CSQ(a64r, a64i);
    if (tid < 64) {
        apar[(h * Nn + lane) * 2]     = a64r;
        apar[(h * Nn + lane) * 2 + 1] = a64i;
    }

    // stage A: Apow[n][t] = a^(63-t); wave wv covers powers 16*wv .. 16*wv+15
    float pr = 1.f, pi = 0.f;
    if (wv == 1) { pr = a16r; pi = a16i; }
    else if (wv == 2) { pr = a32r; pi = a32i; }
    else if (wv == 3) { pr = a48r; pi = a48i; }
    for (int i = 0; i < 16; ++i) {
        int t = 63 - ((wv << 4) + i);
        sh[0][lane][t] = pr;
        sh[1][lane][t] = pi;
        float nr = pr * ar - pi * ai; pi = pr * ai + pi * ar; pr = nr;
    }
    __syncthreads();

    // AF1 fragment stores (bf16-hi only)
    short* A1h = AF1 + (size_t)h * AF1_STRIDE;
    #pragma unroll
    for (int cm = 0; cm < 2; ++cm)
        #pragma unroll
        for (int kt = 0; kt < 2; ++kt) {
            union { short s[8]; short8 v; } uh;
            #pragma unroll
            for (int j = 0; j < 8; ++j)
                uh.s[j] = bf16hi(sh[cm][mrow][kt * 32 + kq * 8 + j]);
            *(short8*)&A1h[((cm * 4 + wv) * 2 + kt) * 512 + lane * 8] = uh.v;
        }
    __syncthreads();

    // stage B: Gre/Gim into sh (G[j][n] = CB * a^(j+1))
    if (tid < 64) {
        cbrL[lane] = cbr;
        float Pr = ar, Pi = ai;
        for (int j = 0; j < 64; ++j) {
            sh[0][j][lane] = cbr * Pr - cbi * Pi;
            sh[1][j][lane] = cbr * Pi + cbi * Pr;
            float nr = Pr * ar - Pi * ai; Pi = Pr * ai + Pi * ar; Pr = nr;
        }
    }
    __syncthreads();
    // Krow -> kb (zero-padded low half): Krow[t] = sum_n Re(CB_n a_n^t)
    if (tid < 64) kb[tid] = 0.f;
    else if (tid < 128) {
        int t2 = tid - 64;
        float s = 0.f;
        if (t2 == 0) { for (int n2 = 0; n2 < 64; ++n2) s += cbrL[n2]; }
        else         { for (int n2 = 0; n2 < 64; ++n2) s += sh[0][t2 - 1][n2]; }
        kb[tid] = s;
    }
    __syncthreads();

    // AF2 fragment stores: A2 = [T | Gre | -Gim], 64x192 (bf16-hi only)
    short* A2h = AF2 + (size_t)h * AF2_STRIDE;
    #pragma unroll
    for (int kt = 0; kt < 6; ++kt) {
        union { short s[8]; short8 v; } uh;
        #pragma unroll
        for (int j = 0; j < 8; ++j) {
            float x;
            if (kt < 2) {
                int kk = kt * 32 + kq * 8 + j;          // m index of T
                x = kb[64 + mrow - kk];                  // T[j][m] = Krow[j-m]
            } else {
                int q2 = kt - 2;
                int nn = (q2 & 1) * 32 + kq * 8 + j;
                x = (q2 >> 1) ? -sh[1][mrow][nn] : sh[0][mrow][nn];
            }
            uh.s[j] = bf16hi(x);
        }
        *(short8*)&A2h[(wv * 6 + kt) * 512 + lane * 8] = uh.v;
    }
}

// ---------------------------------------------------------------------------
// K1 (MFMA scan+chunks). block = (b,h), 4 waves; wave w owns m-tile w.
//  set1: P(64n x 32c) = Apow(64x64) * U(64t x 32c)   [A bf16-hi, U hi/lo]
//  scan: S[c] = a64*S[c-1] + P[c-1] (32 steps, lane = n, waves duplicate,
//        wave w stages bf16 hi/lo S for its c-range into Sb)
//  set2: Y(64j x 32c) = [T|Gre|-Gim](64x192) * [U;Sre;Sim](192x32)
//  epilogue: Y + D*u -> exact GELU -> ypre[b,h,l]
// ---------------------------------------------------------------------------
__global__ __launch_bounds__(256, 4)
void k_scan_chunks(const float* __restrict__ uT, const float* __restrict__ apar,
                   const short* __restrict__ AF1, const short* __restrict__ AF2,
                   const float* __restrict__ D, float* __restrict__ ypre)
{
    __shared__ float P2[64][35][2];        // P (re,im) fp32; aliased as Y later
    __shared__ short Sb[2][2][32][72];     // [split][reim][c][n]

    int bh   = blockIdx.x;
    int h    = bh & (Hn - 1);
    int tid  = threadIdx.x;
    int lane = tid & 63;
    int w    = __builtin_amdgcn_readfirstlane(tid >> 6);
    int l15  = lane & 15;
    int kq   = lane >> 4;

    const float* uRow = uT + (size_t)bh * Ln;
    const short* A1h  = AF1 + (size_t)h * AF1_STRIDE;
    const short* A2h  = AF2 + (size_t)h * AF2_STRIDE;

    // ---- U fragments direct from global (L1), bf16 hi/lo ----
    short8 Uh[2][2], Ul[2][2];             // [kt][ct]
    #pragma unroll
    for (int kt = 0; kt < 2; ++kt)
        #pragma unroll
        for (int ct = 0; ct < 2; ++ct) {
            int c = ct * 16 + l15;
            const float* up = uRow + c * 64 + kt * 32 + kq * 8;
            float4 f0 = *(const float4*)up;
            float4 f1 = *(const float4*)(up + 4);
            float xv[8] = {f0.x, f0.y, f0.z, f0.w, f1.x, f1.y, f1.z, f1.w};
            union { short s[8]; short8 v; } hh, ll;
            #pragma unroll
            for (int j = 0; j < 8; ++j) {
                short hs = bf16hi(xv[j]);
                hh.s[j] = hs;
                ll.s[j] = bf16hi(xv[j] - bf16f(hs));
            }
            Uh[kt][ct] = hh.v;
            Ul[kt][ct] = ll.v;
        }

    // ---- set 1: P = Apow * U ----
    f32x4 Pre_acc[2] = {{0.f,0.f,0.f,0.f},{0.f,0.f,0.f,0.f}};
    f32x4 Pim_acc[2] = {{0.f,0.f,0.f,0.f},{0.f,0.f,0.f,0.f}};
    #pragma unroll
    for (int kt = 0; kt < 2; ++kt) {
        short8 a_re = *(const short8*)&A1h[((0 * 4 + w) * 2 + kt) * 512 + lane * 8];
        short8 a_im = *(const short8*)&A1h[((1 * 4 + w) * 2 + kt) * 512 + lane * 8];
        #pragma unroll
        for (int ct = 0; ct < 2; ++ct) {
            Pre_acc[ct] = MFMA16(a_re, Uh[kt][ct], Pre_acc[ct], 0, 0, 0);
            Pre_acc[ct] = MFMA16(a_re, Ul[kt][ct], Pre_acc[ct], 0, 0, 0);
            Pim_acc[ct] = MFMA16(a_im, Uh[kt][ct], Pim_acc[ct], 0, 0, 0);
            Pim_acc[ct] = MFMA16(a_im, Ul[kt][ct], Pim_acc[ct], 0, 0, 0);
        }
    }
    // P -> LDS (C/D layout: col = lane&15, row = quad*4 + reg)
    #pragma unroll
    for (int ct = 0; ct < 2; ++ct)
        #pragma unroll
        for (int r = 0; r < 4; ++r) {
            int n = (w << 4) + kq * 4 + r;
            int c = ct * 16 + l15;
            *(float2*)&P2[n][c][0] = make_float2(Pre_acc[ct][r], Pim_acc[ct][r]);
        }
    __syncthreads();

    // ---- scan (lane = n); every wave duplicates, wave w stages its c-range ----
    {
        int n = lane;
        float a64r = apar[(h * Nn + n) * 2];
        float a64i = apar[(h * Nn + n) * 2 + 1];
        float sr = 0.f, si = 0.f;
        for (int c = 0; c < NC; ++c) {
            if ((c >> 3) == w) {
                short hr = bf16hi(sr); short lr = bf16hi(sr - bf16f(hr));
                short hi2 = bf16hi(si); short li = bf16hi(si - bf16f(hi2));
                Sb[0][0][c][n] = hr;  Sb[1][0][c][n] = lr;
                Sb[0][1][c][n] = hi2; Sb[1][1][c][n] = li;
            }
            float2 pv = *(float2*)&P2[n][c][0];
            float nsr = fmaf(a64r, sr, fmaf(-a64i, si, pv.x));
            float nsi = fmaf(a64i, sr, fmaf(a64r, si, pv.y));
            sr = nsr; si = nsi;
        }
    }
    __syncthreads();

    // ---- set 2: Y = [T|Gre|-Gim] * [U;Sre;Sim] ----
    f32x4 Yacc[2] = {{0.f,0.f,0.f,0.f},{0.f,0.f,0.f,0.f}};
    #pragma unroll
    for (int kt = 0; kt < 6; ++kt) {
        short8 a_h = *(const short8*)&A2h[(w * 6 + kt) * 512 + lane * 8];
        #pragma unroll
        for (int ct = 0; ct < 2; ++ct) {
            short8 bhf, blf;
            if (kt < 2) { bhf = Uh[kt][ct]; blf = Ul[kt][ct]; }
            else {
                int q2 = kt - 2, reim = q2 >> 1;
                int nb = (q2 & 1) * 32 + kq * 8;
                int c  = ct * 16 + l15;
                bhf = *(const short8*)&Sb[0][reim][c][nb];
                blf = *(const short8*)&Sb[1][reim][c][nb];
            }
            Yacc[ct] = MFMA16(a_h, bhf, Yacc[ct], 0, 0, 0);
            Yacc[ct] = MFMA16(a_h, blf, Yacc[ct], 0, 0, 0);
        }
    }
    // Y -> LDS (reuse P2 region, stride 70 floats)
    float* Yl = (float*)P2;
    #pragma unroll
    for (int ct = 0; ct < 2; ++ct)
        #pragma unroll
        for (int r = 0; r < 4; ++r) {
            int j = (w << 4) + kq * 4 + r;
            int c = ct * 16 + l15;
            Yl[j * 70 + c] = Yacc[ct][r];
        }
    __syncthreads();

    // ---- epilogue: +D*u, exact GELU, coalesced store ----
    float Dh = D[h];
    #pragma unroll
    for (int i = 0; i < 8; ++i) {
        int c = (w << 3) + i;
        float y  = Yl[lane * 70 + c];
        float uv = uRow[c * 64 + lane];
        float yv = fmaf(Dh, uv, y);
        float g  = 0.5f * yv * (1.f + erff(yv * 0.70710678118654752f));
        ypre[(size_t)bh * Ln + c * 64 + lane] = g;
    }
}

// ---------------------------------------------------------------------------
// K2: LayerNorm over H; float4 global I/O, transposed LDS tile.
// ---------------------------------------------------------------------------
__global__ __launch_bounds__(256)
void k_ln(const float* __restrict__ ypre, const float* __restrict__ gamma,
          const float* __restrict__ beta, float* __restrict__ out)
{
    __shared__ float tile[32][260];
    int b  = blockIdx.y;
    int l0 = blockIdx.x << 5;
    int t  = threadIdx.x;

    #pragma unroll
    for (int i = 0; i < 8; ++i) {
        int idx = (i << 8) + t;
        int hh  = idx >> 3, lo4 = idx & 7;
        float4 v = *(const float4*)&ypre[((size_t)b * Hn + hh) * Ln + l0 + (lo4 << 2)];
        tile[(lo4 << 2) + 0][hh] = v.x;
        tile[(lo4 << 2) + 1][hh] = v.y;
        tile[(lo4 << 2) + 2][hh] = v.z;
        tile[(lo4 << 2) + 3][hh] = v.w;
    }
    __syncthreads();

    int wv = t >> 6, lane = t & 63;
    float4 g4 = *(const float4*)&gamma[lane << 2];
    float4 b4 = *(const float4*)&beta[lane << 2];
    #pragma unroll
    for (int k = 0; k < 8; ++k) {
        int l = (k << 2) | wv;
        float4 v = *(const float4*)&tile[l][lane << 2];
        float sum = (v.x + v.y) + (v.z + v.w);
        float sq  = fmaf(v.x, v.x, fmaf(v.y, v.y, fmaf(v.z, v.z, v.w * v.w)));
        #pragma unroll
        for (int off = 32; off; off >>= 1) {
            sum += __shfl_xor(sum, off);
            sq  += __shfl_xor(sq, off);
        }
        float mean = sum * (1.f / 256.f);
        float var  = sq * (1.f / 256.f) - mean * mean;
        float rs   = rsqrtf(var + 1e-5f);
        float4 o;
        o.x = (v.x - mean) * rs * g4.x + b4.x;
        o.y = (v.y - mean) * rs * g4.y + b4.y;
        o.z = (v.z - mean) * rs * g4.z + b4.z;
        o.w = (v.w - mean) * rs * g4.w + b4.w;
        *(float4*)&out[((size_t)b * Ln + l0 + l) * Hn + (lane << 2)] = o;
    }
}

// ---------------------------------------------------------------------------
extern "C" void kernel_launch(void* const* d_in, const int* in_sizes, int n_in,
                              void* d_out, int out_size, void* d_ws, size_t ws_size,
                              hipStream_t stream)
{
    const float* u     = (const float*)d_in[0];
    const float* lnr   = (const float*)d_in[1];
    const float* im    = (const float*)d_in[2];
    const float* Bre   = (const float*)d_in[3];
    const float* Bim   = (const float*)d_in[4];
    const float* Cre   = (const float*)d_in[5];
    const float* Cim   = (const float*)d_in[6];
    const float* Dp    = (const float*)d_in[7];
    const float* lstep = (const float*)d_in[8];
    const float* gam   = (const float*)d_in[9];
    const float* bet   = (const float*)d_in[10];
    float* out = (float*)d_out;

    // workspace carve
    float* ws   = (float*)d_ws;
    float* uT   = ws;                                   // 2,097,152 f
    float* apar = uT + (size_t)Bn * Hn * Ln;            //    32,768 f
    float* ypre = apar + (size_t)Hn * Nn * 2;           // 2,097,152 f
    short* AF1  = (short*)(ypre + (size_t)Bn * Hn * Ln);// Hn*8192 sh (16B-aligned)
    short* AF2  = AF1 + (size_t)Hn * AF1_STRIDE;        // Hn*12288 sh

    k_pre<<<768, 256, 0, stream>>>(u, uT, lnr, im, Bre, Bim, Cre, Cim, lstep, AF1, AF2, apar);
    k_scan_chunks<<<Bn * Hn, 256, 0, stream>>>(uT, apar, AF1, AF2, Dp, ypre);
    k_ln<<<dim3(Ln / 32, Bn), 256, 0, stream>>>(ypre, gam, bet, out);
}